// Round 3
// baseline (957.531 us; speedup 1.0000x reference)
//
#include <hip/hip_runtime.h>

// PAWSA (Swin window attention): x @ Wqkv -> per-window biased softmax attn -> @ Wproj
// Round 2 resubmit (broker timeout x2; kernel unchanged from round 1):
//   prep (cvt x->bf16, W^T->bf16, bias table) -> GEMM1 (qkv) -> attn -> GEMM2 (out)
// GEMM: 128x128xK64 tiles, 4 waves x (64x64), mfma_f32_16x16x32_bf16, reg-staged
// double-buffered LDS, 2-phase schedule, XCD-contiguous block swizzle (A-tile L2 reuse).
// Attention: 1 wave per (window, head); S=QK^T via MFMA, wave-parallel softmax
// (16-lane shfl_xor groups), P/V^T in LDS, PV via MFMA, 1/sum folded into store.

typedef unsigned short u16;
typedef __attribute__((ext_vector_type(8))) short bf16x8;
typedef __attribute__((ext_vector_type(4))) float f32x4;

#define M_TOT 100352   // 2048 windows * 49 tokens
#define KDIM  512

__device__ __forceinline__ u16 f2bf(float x) {
  union { float f; unsigned u; } v; v.f = x;
  unsigned r = v.u + 0x7fffu + ((v.u >> 16) & 1u);   // RNE
  return (u16)(r >> 16);
}

// ---------------- prep kernels ----------------
__global__ void k_cvt(const float* __restrict__ in, u16* __restrict__ out, int n4) {
  int i = blockIdx.x * 256 + threadIdx.x;
  if (i >= n4) return;
  float4 v = ((const float4*)in)[i];
  ushort4 o; o.x = f2bf(v.x); o.y = f2bf(v.y); o.z = f2bf(v.z); o.w = f2bf(v.w);
  ((ushort4*)out)[i] = o;
}

// out[n*512 + k] = bf16(in[k*Ncols + n])   (W^T, K fixed = 512)
__global__ void k_cvtT(const float* __restrict__ in, u16* __restrict__ out,
                       int Ncols, int total) {
  int i = blockIdx.x * 256 + threadIdx.x;
  if (i >= total) return;
  int n = i >> 9, k = i & 511;
  out[i] = f2bf(in[(size_t)k * Ncols + n]);
}

// bias_tbl[h*2401 + n*49 + m] = rpb[rel_index[n*49+m]*16 + h]
__global__ void k_bias(const float* __restrict__ rpb, const int* __restrict__ ridx,
                       float* __restrict__ tbl) {
  int i = blockIdx.x * 256 + threadIdx.x;
  if (i >= 16 * 2401) return;
  int h = i / 2401, nm = i - h * 2401;
  tbl[i] = rpb[ridx[nm] * 16 + h];
}

// ---------------- GEMM: C[M x N] = A[M x 512] * BT[N x 512]^T + bias ----------------
template<int OUTBF>
__global__ __launch_bounds__(256)
void k_gemm(const u16* __restrict__ A, const u16* __restrict__ BT,
            const float* __restrict__ bias, void* __restrict__ outp,
            int N, int ntiles) {
  __shared__ u16 smem[2][2][128 * 64];          // [buf][A/B][row][k]  64 KB
  const int tid  = threadIdx.x;
  const int total = (int)gridDim.x;             // multiple of 8 by construction
  const int logical = ((int)blockIdx.x & 7) * (total >> 3) + ((int)blockIdx.x >> 3);
  const int mtb = logical / ntiles, ntb = logical % ntiles;
  const int lane = tid & 63, wave = tid >> 6;
  const int l15 = lane & 15, g4 = lane >> 4;
  const int wm = (wave >> 1) * 64, wn = (wave & 1) * 64;

  const char* gA = (const char*)(A  + (size_t)mtb * (128 * KDIM));
  const char* gB = (const char*)(BT + (size_t)ntb * (128 * KDIM));

  int rowp[4], inpp[4];
#pragma unroll
  for (int i = 0; i < 4; ++i) {
    int p = (i * 256 + tid) * 16;               // byte pos in 16 KB tile
    rowp[i] = p >> 7;                           // row (128 B per row)
    inpp[i] = p & 127;                          // byte within row
  }

  bf16x8 ra[4], rb[4];
#pragma unroll
  for (int i = 0; i < 4; ++i) {
    ra[i] = *(const bf16x8*)(gA + (size_t)rowp[i] * 1024 + inpp[i]);
    rb[i] = *(const bf16x8*)(gB + (size_t)rowp[i] * 1024 + inpp[i]);
  }

  f32x4 zero4 = {0.f, 0.f, 0.f, 0.f};
  f32x4 acc[4][4];
#pragma unroll
  for (int a = 0; a < 4; ++a)
#pragma unroll
    for (int b = 0; b < 4; ++b) acc[a][b] = zero4;

#pragma unroll
  for (int i = 0; i < 4; ++i) {                 // commit stage 0
    *(bf16x8*)((char*)(&smem[0][0][0]) + (i * 256 + tid) * 16) = ra[i];
    *(bf16x8*)((char*)(&smem[0][1][0]) + (i * 256 + tid) * 16) = rb[i];
  }
  __syncthreads();

  for (int ks = 0; ks < 8; ++ks) {
    const int buf = ks & 1;
    if (ks < 7) {                               // issue next-stage loads early
#pragma unroll
      for (int i = 0; i < 4; ++i) {
        ra[i] = *(const bf16x8*)(gA + (size_t)rowp[i] * 1024 + (ks + 1) * 128 + inpp[i]);
        rb[i] = *(const bf16x8*)(gB + (size_t)rowp[i] * 1024 + (ks + 1) * 128 + inpp[i]);
      }
    }
    const u16* As = &smem[buf][0][0];
    const u16* Bs = &smem[buf][1][0];
#pragma unroll
    for (int kk = 0; kk < 2; ++kk) {
      bf16x8 af[4], bg[4];
#pragma unroll
      for (int mt = 0; mt < 4; ++mt)
        af[mt] = *(const bf16x8*)(As + (wm + mt * 16 + l15) * 64 + kk * 32 + g4 * 8);
#pragma unroll
      for (int nt = 0; nt < 4; ++nt)
        bg[nt] = *(const bf16x8*)(Bs + (wn + nt * 16 + l15) * 64 + kk * 32 + g4 * 8);
#pragma unroll
      for (int mt = 0; mt < 4; ++mt)
#pragma unroll
        for (int nt = 0; nt < 4; ++nt)
          acc[mt][nt] = __builtin_amdgcn_mfma_f32_16x16x32_bf16(af[mt], bg[nt], acc[mt][nt], 0, 0, 0);
    }
    __syncthreads();
    if (ks < 7) {
      const int nb = buf ^ 1;
#pragma unroll
      for (int i = 0; i < 4; ++i) {
        *(bf16x8*)((char*)(&smem[nb][0][0]) + (i * 256 + tid) * 16) = ra[i];
        *(bf16x8*)((char*)(&smem[nb][1][0]) + (i * 256 + tid) * 16) = rb[i];
      }
      __syncthreads();
    }
  }

  u16*  outb = (u16*)outp;
  float* outf = (float*)outp;
#pragma unroll
  for (int nt = 0; nt < 4; ++nt) {
    const int cg = ntb * 128 + wn + nt * 16 + l15;
    const float bv = bias[cg];
#pragma unroll
    for (int mt = 0; mt < 4; ++mt) {
      const size_t rg = (size_t)mtb * 128 + wm + mt * 16 + g4 * 4;
#pragma unroll
      for (int i2 = 0; i2 < 4; ++i2) {
        float v = acc[mt][nt][i2] + bv;
        size_t off = (rg + i2) * (size_t)N + cg;
        if (OUTBF) outb[off] = f2bf(v); else outf[off] = v;
      }
    }
  }
}

// ---------------- attention: 1 block = (window, 4 heads), 1 wave per head ----------------
__global__ __launch_bounds__(256)
void k_attn(const u16* __restrict__ qkv, const float* __restrict__ btbl,
            u16* __restrict__ aout) {
  __shared__ u16 sm[4][6912];                   // per wave: P[64][72] + V^T[32][72]
  const int tid = threadIdx.x;
  const int wave = tid >> 6, lane = tid & 63;
  const int l15 = lane & 15, g4 = lane >> 4;
  const int win  = (int)blockIdx.x >> 2;
  const int head = ((int)blockIdx.x & 3) * 4 + wave;
  const u16* base = qkv + (size_t)win * (49 * 1536);
  const int hoff = head * 32;
  u16* plds = sm[wave];
  u16* vt   = sm[wave] + 4608;

  // stage V^T[d][m] = V[m][d]; 256 tasks cover r in [0,64) x 4 col-groups.
  // rows r>=49 are explicit ZEROS (PV reads m up to 63; junk*0 could be NaN).
  {
    bf16x8 zz = {0, 0, 0, 0, 0, 0, 0, 0};
#pragma unroll
    for (int it = 0; it < 4; ++it) {
      int task = it * 64 + lane;
      int r = task >> 2, cg2 = task & 3;
      bf16x8 vv = zz;
      if (r < 49)
        vv = *(const bf16x8*)(base + (size_t)r * 1536 + 1024 + hoff + cg2 * 8);
#pragma unroll
      for (int j = 0; j < 8; ++j) vt[(cg2 * 8 + j) * 72 + r] = (u16)vv[j];
    }
  }

  // Q/K fragments straight from global (A: row=l15,k=8*g4+j ; B: col=l15,k=8*g4+j)
  bf16x8 aq[4], bk[4];
#pragma unroll
  for (int t = 0; t < 4; ++t) {
    aq[t] = *(const bf16x8*)(base + (size_t)(t * 16 + l15) * 1536 + hoff + g4 * 8);
    bk[t] = *(const bf16x8*)(base + (size_t)(t * 16 + l15) * 1536 + 512 + hoff + g4 * 8);
  }
  f32x4 zero4 = {0.f, 0.f, 0.f, 0.f};
  f32x4 s[4][4];
#pragma unroll
  for (int mt = 0; mt < 4; ++mt)
#pragma unroll
    for (int nt = 0; nt < 4; ++nt)
      s[mt][nt] = __builtin_amdgcn_mfma_f32_16x16x32_bf16(aq[mt], bk[nt], zero4, 0, 0, 0);

  // softmax over cols (keys); C layout: row = 16*mt + 4*g4 + i, col = 16*nt + l15
  const float* bt = btbl + head * 2401;
  const float scale = 0.17677669529663687f;     // 1/sqrt(32)
  float recip[4][4];
#pragma unroll
  for (int mt = 0; mt < 4; ++mt) {
#pragma unroll
    for (int i = 0; i < 4; ++i) {
      const int row = mt * 16 + g4 * 4 + i;
      const int rowc = row < 49 ? row : 48;
      float lv[4];
      float mx = -3.0e38f;
#pragma unroll
      for (int nt = 0; nt < 4; ++nt) {
        const int col = nt * 16 + l15;
        float v = (col < 49) ? (s[mt][nt][i] * scale + bt[rowc * 49 + col]) : -3.0e38f;
        lv[nt] = v;
        mx = fmaxf(mx, v);
      }
      mx = fmaxf(mx, __shfl_xor(mx, 1));
      mx = fmaxf(mx, __shfl_xor(mx, 2));
      mx = fmaxf(mx, __shfl_xor(mx, 4));
      mx = fmaxf(mx, __shfl_xor(mx, 8));
      float sum = 0.f;
#pragma unroll
      for (int nt = 0; nt < 4; ++nt) {
        float p = __expf(lv[nt] - mx);
        lv[nt] = p;
        sum += p;
      }
      sum += __shfl_xor(sum, 1);
      sum += __shfl_xor(sum, 2);
      sum += __shfl_xor(sum, 4);
      sum += __shfl_xor(sum, 8);
      recip[mt][i] = 1.0f / sum;
#pragma unroll
      for (int nt = 0; nt < 4; ++nt)
        plds[row * 72 + nt * 16 + l15] = f2bf(lv[nt]);   // unnormalized P
    }
  }

  // O = P @ V  (A from plds, B from vt); normalize by recip at store
  f32x4 o[4][2];
#pragma unroll
  for (int mt = 0; mt < 4; ++mt)
#pragma unroll
    for (int dt = 0; dt < 2; ++dt) o[mt][dt] = zero4;
#pragma unroll
  for (int kt = 0; kt < 2; ++kt) {
    bf16x8 pa[4], vb[2];
#pragma unroll
    for (int mt = 0; mt < 4; ++mt)
      pa[mt] = *(const bf16x8*)(plds + (mt * 16 + l15) * 72 + kt * 32 + g4 * 8);
#pragma unroll
    for (int dt = 0; dt < 2; ++dt)
      vb[dt] = *(const bf16x8*)(vt + (dt * 16 + l15) * 72 + kt * 32 + g4 * 8);
#pragma unroll
    for (int mt = 0; mt < 4; ++mt)
#pragma unroll
      for (int dt = 0; dt < 2; ++dt)
        o[mt][dt] = __builtin_amdgcn_mfma_f32_16x16x32_bf16(pa[mt], vb[dt], o[mt][dt], 0, 0, 0);
  }

#pragma unroll
  for (int mt = 0; mt < 4; ++mt) {
#pragma unroll
    for (int i = 0; i < 4; ++i) {
      const int row = mt * 16 + g4 * 4 + i;
      if (row < 49) {
        u16* orow = aout + (size_t)(win * 49 + row) * 512 + hoff;
#pragma unroll
        for (int dt = 0; dt < 2; ++dt)
          orow[dt * 16 + l15] = f2bf(o[mt][dt][i] * recip[mt][i]);
      }
    }
  }
}

// ---------------- launcher ----------------
extern "C" void kernel_launch(void* const* d_in, const int* in_sizes, int n_in,
                              void* d_out, int out_size, void* d_ws, size_t ws_size,
                              hipStream_t stream) {
  const float* x      = (const float*)d_in[0];
  const float* w_qkv  = (const float*)d_in[1];
  const float* b_qkv  = (const float*)d_in[2];
  const float* rpb    = (const float*)d_in[3];
  const float* w_proj = (const float*)d_in[4];
  const float* b_proj = (const float*)d_in[5];
  const int*   ridx   = (const int*)d_in[6];
  float* out = (float*)d_out;

  // ws layout (bytes). x_bf16 region is reused for attnout after GEMM1.
  const size_t o_x   = 0;                          // 100352*512*2     = 102,760,448
  const size_t o_qkv = 102760448;                  // 100416*1536*2    = 308,477,952 (64 slack rows)
  const size_t o_wq  = o_qkv + 308477952;          // 1536*512*2       =   1,572,864
  const size_t o_wp  = o_wq + 1572864;             // 512*512*2        =     524,288
  const size_t o_bt  = o_wp + 524288;              // 16*49*49*4       =     153,664
  const size_t need  = o_bt + 153664;              // ~394 MiB
  if (ws_size < need) return;                      // failure signature: absmax == 0.171875

  char* ws = (char*)d_ws;
  u16*   xbf  = (u16*)(ws + o_x);
  u16*   qkv  = (u16*)(ws + o_qkv);
  u16*   wqT  = (u16*)(ws + o_wq);
  u16*   wpT  = (u16*)(ws + o_wp);
  float* btbl = (float*)(ws + o_bt);

  k_cvt  <<<50176, 256, 0, stream>>>(x, xbf, 12845056);          // x -> bf16
  k_cvtT <<<3072,  256, 0, stream>>>(w_qkv, wqT, 1536, 786432);  // Wqkv^T -> bf16
  k_cvtT <<<1024,  256, 0, stream>>>(w_proj, wpT, 512, 262144);  // Wproj^T -> bf16
  k_bias <<<151,   256, 0, stream>>>(rpb, ridx, btbl);           // bias table

  k_gemm<1><<<784 * 12, 256, 0, stream>>>(xbf, wqT, b_qkv, qkv, 1536, 12);  // QKV
  k_attn   <<<2048 * 4, 256, 0, stream>>>(qkv, btbl, xbf);                  // attn -> xbf region
  k_gemm<0><<<784 * 4,  256, 0, stream>>>(xbf, wpT, b_proj, out, 512, 4);   // proj -> d_out
}

// Round 4
// 926.524 us; speedup vs baseline: 1.0335x; 1.0335x over previous
//
#include <hip/hip_runtime.h>

// PAWSA (Swin window attention): x @ Wqkv -> per-window biased softmax attn -> @ Wproj
// Round 3: GEMMs moved to m97 structure (global_load_lds width=16, single-buffer LDS,
// 2-barrier K-loop) -- replaces reg-staging (576 TF plateau -> expect ~850 TF).
// Attn: LDS strides 72->68 (55.3KB -> 52.2KB => 3 blocks/CU instead of 2).

typedef unsigned short u16;
typedef __attribute__((ext_vector_type(8))) short bf16x8;
typedef __attribute__((ext_vector_type(4))) float f32x4;

#define M_TOT 100352   // 2048 windows * 49 tokens
#define KDIM  512

// async global->LDS, 16B per lane; LDS dest is wave-uniform base + lane*16 (m104)
#define GLD16(gp, lp) __builtin_amdgcn_global_load_lds( \
    (const __attribute__((address_space(1))) void*)(gp), \
    (__attribute__((address_space(3))) void*)(lp), 16, 0, 0)

__device__ __forceinline__ u16 f2bf(float x) {
  union { float f; unsigned u; } v; v.f = x;
  unsigned r = v.u + 0x7fffu + ((v.u >> 16) & 1u);   // RNE
  return (u16)(r >> 16);
}

// ---------------- prep kernels ----------------
__global__ void k_cvt(const float* __restrict__ in, u16* __restrict__ out, int n4) {
  int i = blockIdx.x * 256 + threadIdx.x;
  if (i >= n4) return;
  float4 v = ((const float4*)in)[i];
  ushort4 o; o.x = f2bf(v.x); o.y = f2bf(v.y); o.z = f2bf(v.z); o.w = f2bf(v.w);
  ((ushort4*)out)[i] = o;
}

// out[n*512 + k] = bf16(in[k*Ncols + n])   (W^T, K fixed = 512)
__global__ void k_cvtT(const float* __restrict__ in, u16* __restrict__ out,
                       int Ncols, int total) {
  int i = blockIdx.x * 256 + threadIdx.x;
  if (i >= total) return;
  int n = i >> 9, k = i & 511;
  out[i] = f2bf(in[(size_t)k * Ncols + n]);
}

// bias_tbl[h*2401 + n*49 + m] = rpb[rel_index[n*49+m]*16 + h]
__global__ void k_bias(const float* __restrict__ rpb, const int* __restrict__ ridx,
                       float* __restrict__ tbl) {
  int i = blockIdx.x * 256 + threadIdx.x;
  if (i >= 16 * 2401) return;
  int h = i / 2401, nm = i - h * 2401;
  tbl[i] = rpb[ridx[nm] * 16 + h];
}

// ---------------- GEMM: C[M x N] = A[M x 512] * BT[N x 512]^T + bias ----------------
// m97 structure: 128x128xBK64, 4 waves x (64x64), global_load_lds staging,
// single LDS buffer (32 KB), 2 barriers per K-step.
template<int OUTBF>
__global__ __launch_bounds__(256)
void k_gemm(const u16* __restrict__ A, const u16* __restrict__ BT,
            const float* __restrict__ bias, void* __restrict__ outp,
            int N, int ntiles) {
  __shared__ u16 As[128 * 64];                  // [row][k] linear, 128 B/row
  __shared__ u16 Bs[128 * 64];
  const int tid  = threadIdx.x;
  const int total = (int)gridDim.x;             // multiple of 8 by construction
  const int logical = ((int)blockIdx.x & 7) * (total >> 3) + ((int)blockIdx.x >> 3);
  const int mtb = logical / ntiles, ntb = logical % ntiles;
  const int lane = tid & 63, wave = tid >> 6;
  const int l15 = lane & 15, g4 = lane >> 4;
  const int wm = (wave >> 1) * 64, wn = (wave & 1) * 64;

  const char* gA = (const char*)(A  + (size_t)mtb * (128 * KDIM));
  const char* gB = (const char*)(BT + (size_t)ntb * (128 * KDIM));
  // one global_load_lds covers 8 rows (8 x 128 B = 1 KB): lane l -> row l>>3, byte (l&7)*16
  const int lrow = lane >> 3;
  const int lcol = (lane & 7) * 16;

  f32x4 zero4 = {0.f, 0.f, 0.f, 0.f};
  f32x4 acc[4][4];
#pragma unroll
  for (int a = 0; a < 4; ++a)
#pragma unroll
    for (int b = 0; b < 4; ++b) acc[a][b] = zero4;

  // ---- stage K-step 0 ----
#pragma unroll
  for (int i = 0; i < 4; ++i) {
    const int r0 = wave * 32 + i * 8;
    GLD16(gA + (size_t)(r0 + lrow) * 1024 + lcol, &As[r0 * 64]);
    GLD16(gB + (size_t)(r0 + lrow) * 1024 + lcol, &Bs[r0 * 64]);
  }
  __syncthreads();                              // vmcnt(0) drain + barrier

  for (int ks = 0; ks < 8; ++ks) {
#pragma unroll
    for (int kk = 0; kk < 2; ++kk) {
      bf16x8 af[4], bg[4];
#pragma unroll
      for (int mt = 0; mt < 4; ++mt)
        af[mt] = *(const bf16x8*)(As + (wm + mt * 16 + l15) * 64 + kk * 32 + g4 * 8);
#pragma unroll
      for (int nt = 0; nt < 4; ++nt)
        bg[nt] = *(const bf16x8*)(Bs + (wn + nt * 16 + l15) * 64 + kk * 32 + g4 * 8);
#pragma unroll
      for (int mt = 0; mt < 4; ++mt)
#pragma unroll
        for (int nt = 0; nt < 4; ++nt)
          acc[mt][nt] = __builtin_amdgcn_mfma_f32_16x16x32_bf16(af[mt], bg[nt], acc[mt][nt], 0, 0, 0);
    }
    __syncthreads();                            // all waves done reading LDS
    if (ks < 7) {
      const int koff = (ks + 1) * 128;          // byte offset of next K-slice
#pragma unroll
      for (int i = 0; i < 4; ++i) {
        const int r0 = wave * 32 + i * 8;
        GLD16(gA + (size_t)(r0 + lrow) * 1024 + koff + lcol, &As[r0 * 64]);
        GLD16(gB + (size_t)(r0 + lrow) * 1024 + koff + lcol, &Bs[r0 * 64]);
      }
      __syncthreads();                          // drain + barrier
    }
  }

  u16*  outb = (u16*)outp;
  float* outf = (float*)outp;
#pragma unroll
  for (int nt = 0; nt < 4; ++nt) {
    const int cg = ntb * 128 + wn + nt * 16 + l15;
    const float bv = bias[cg];
#pragma unroll
    for (int mt = 0; mt < 4; ++mt) {
      const size_t rg = (size_t)mtb * 128 + wm + mt * 16 + g4 * 4;
#pragma unroll
      for (int i2 = 0; i2 < 4; ++i2) {
        float v = acc[mt][nt][i2] + bv;
        size_t off = (rg + i2) * (size_t)N + cg;
        if (OUTBF) outb[off] = f2bf(v); else outf[off] = v;
      }
    }
  }
}

// ---------------- attention: 1 block = (window, 4 heads), 1 wave per head ----------------
__global__ __launch_bounds__(256)
void k_attn(const u16* __restrict__ qkv, const float* __restrict__ btbl,
            u16* __restrict__ aout) {
  __shared__ u16 sm[4][6528];                   // per wave: P[64][68] + V^T[32][68] = 52224 B total
  const int tid = threadIdx.x;
  const int wave = tid >> 6, lane = tid & 63;
  const int l15 = lane & 15, g4 = lane >> 4;
  const int win  = (int)blockIdx.x >> 2;
  const int head = ((int)blockIdx.x & 3) * 4 + wave;
  const u16* base = qkv + (size_t)win * (49 * 1536);
  const int hoff = head * 32;
  u16* plds = sm[wave];
  u16* vt   = sm[wave] + 4352;

  // stage V^T[d][m] = V[m][d]; 256 tasks cover r in [0,64) x 4 col-groups.
  // rows r>=49 are explicit ZEROS (PV reads m up to 63; junk*0 could be NaN).
  {
    bf16x8 zz = {0, 0, 0, 0, 0, 0, 0, 0};
#pragma unroll
    for (int it = 0; it < 4; ++it) {
      int task = it * 64 + lane;
      int r = task >> 2, cg2 = task & 3;
      bf16x8 vv = zz;
      if (r < 49)
        vv = *(const bf16x8*)(base + (size_t)r * 1536 + 1024 + hoff + cg2 * 8);
#pragma unroll
      for (int j = 0; j < 8; ++j) vt[(cg2 * 8 + j) * 68 + r] = (u16)vv[j];
    }
  }

  // Q/K fragments straight from global (A: row=l15,k=8*g4+j ; B: col=l15,k=8*g4+j)
  bf16x8 aq[4], bk[4];
#pragma unroll
  for (int t = 0; t < 4; ++t) {
    aq[t] = *(const bf16x8*)(base + (size_t)(t * 16 + l15) * 1536 + hoff + g4 * 8);
    bk[t] = *(const bf16x8*)(base + (size_t)(t * 16 + l15) * 1536 + 512 + hoff + g4 * 8);
  }
  f32x4 zero4 = {0.f, 0.f, 0.f, 0.f};
  f32x4 s[4][4];
#pragma unroll
  for (int mt = 0; mt < 4; ++mt)
#pragma unroll
    for (int nt = 0; nt < 4; ++nt)
      s[mt][nt] = __builtin_amdgcn_mfma_f32_16x16x32_bf16(aq[mt], bk[nt], zero4, 0, 0, 0);

  // softmax over cols (keys); C layout: row = 16*mt + 4*g4 + i, col = 16*nt + l15
  const float* bt = btbl + head * 2401;
  const float scale = 0.17677669529663687f;     // 1/sqrt(32)
  float recip[4][4];
#pragma unroll
  for (int mt = 0; mt < 4; ++mt) {
#pragma unroll
    for (int i = 0; i < 4; ++i) {
      const int row = mt * 16 + g4 * 4 + i;
      const int rowc = row < 49 ? row : 48;
      float lv[4];
      float mx = -3.0e38f;
#pragma unroll
      for (int nt = 0; nt < 4; ++nt) {
        const int col = nt * 16 + l15;
        float v = (col < 49) ? (s[mt][nt][i] * scale + bt[rowc * 49 + col]) : -3.0e38f;
        lv[nt] = v;
        mx = fmaxf(mx, v);
      }
      mx = fmaxf(mx, __shfl_xor(mx, 1));
      mx = fmaxf(mx, __shfl_xor(mx, 2));
      mx = fmaxf(mx, __shfl_xor(mx, 4));
      mx = fmaxf(mx, __shfl_xor(mx, 8));
      float sum = 0.f;
#pragma unroll
      for (int nt = 0; nt < 4; ++nt) {
        float p = __expf(lv[nt] - mx);
        lv[nt] = p;
        sum += p;
      }
      sum += __shfl_xor(sum, 1);
      sum += __shfl_xor(sum, 2);
      sum += __shfl_xor(sum, 4);
      sum += __shfl_xor(sum, 8);
      recip[mt][i] = 1.0f / sum;
#pragma unroll
      for (int nt = 0; nt < 4; ++nt)
        plds[row * 68 + nt * 16 + l15] = f2bf(lv[nt]);   // unnormalized P
    }
  }

  // O = P @ V  (A from plds, B from vt); normalize by recip at store
  f32x4 o[4][2];
#pragma unroll
  for (int mt = 0; mt < 4; ++mt)
#pragma unroll
    for (int dt = 0; dt < 2; ++dt) o[mt][dt] = zero4;
#pragma unroll
  for (int kt = 0; kt < 2; ++kt) {
    bf16x8 pa[4], vb[2];
#pragma unroll
    for (int mt = 0; mt < 4; ++mt)
      pa[mt] = *(const bf16x8*)(plds + (mt * 16 + l15) * 68 + kt * 32 + g4 * 8);
#pragma unroll
    for (int dt = 0; dt < 2; ++dt)
      vb[dt] = *(const bf16x8*)(vt + (dt * 16 + l15) * 68 + kt * 32 + g4 * 8);
#pragma unroll
    for (int mt = 0; mt < 4; ++mt)
#pragma unroll
      for (int dt = 0; dt < 2; ++dt)
        o[mt][dt] = __builtin_amdgcn_mfma_f32_16x16x32_bf16(pa[mt], vb[dt], o[mt][dt], 0, 0, 0);
  }

#pragma unroll
  for (int mt = 0; mt < 4; ++mt) {
#pragma unroll
    for (int i = 0; i < 4; ++i) {
      const int row = mt * 16 + g4 * 4 + i;
      if (row < 49) {
        u16* orow = aout + (size_t)(win * 49 + row) * 512 + hoff;
#pragma unroll
        for (int dt = 0; dt < 2; ++dt)
          orow[dt * 16 + l15] = f2bf(o[mt][dt][i] * recip[mt][i]);
      }
    }
  }
}

// ---------------- launcher ----------------
extern "C" void kernel_launch(void* const* d_in, const int* in_sizes, int n_in,
                              void* d_out, int out_size, void* d_ws, size_t ws_size,
                              hipStream_t stream) {
  const float* x      = (const float*)d_in[0];
  const float* w_qkv  = (const float*)d_in[1];
  const float* b_qkv  = (const float*)d_in[2];
  const float* rpb    = (const float*)d_in[3];
  const float* w_proj = (const float*)d_in[4];
  const float* b_proj = (const float*)d_in[5];
  const int*   ridx   = (const int*)d_in[6];
  float* out = (float*)d_out;

  // ws layout (bytes). x_bf16 region is reused for attnout after GEMM1.
  const size_t o_x   = 0;                          // 100352*512*2     = 102,760,448
  const size_t o_qkv = 102760448;                  // 100416*1536*2    = 308,477,952 (64 slack rows)
  const size_t o_wq  = o_qkv + 308477952;          // 1536*512*2       =   1,572,864
  const size_t o_wp  = o_wq + 1572864;             // 512*512*2        =     524,288
  const size_t o_bt  = o_wp + 524288;              // 16*49*49*4       =     153,664
  const size_t need  = o_bt + 153664;              // ~394 MiB
  if (ws_size < need) return;                      // failure signature: absmax == 0.171875

  char* ws = (char*)d_ws;
  u16*   xbf  = (u16*)(ws + o_x);
  u16*   qkv  = (u16*)(ws + o_qkv);
  u16*   wqT  = (u16*)(ws + o_wq);
  u16*   wpT  = (u16*)(ws + o_wp);
  float* btbl = (float*)(ws + o_bt);

  k_cvt  <<<50176, 256, 0, stream>>>(x, xbf, 12845056);          // x -> bf16
  k_cvtT <<<3072,  256, 0, stream>>>(w_qkv, wqT, 1536, 786432);  // Wqkv^T -> bf16
  k_cvtT <<<1024,  256, 0, stream>>>(w_proj, wpT, 512, 262144);  // Wproj^T -> bf16
  k_bias <<<151,   256, 0, stream>>>(rpb, ridx, btbl);           // bias table

  k_gemm<1><<<784 * 12, 256, 0, stream>>>(xbf, wqT, b_qkv, qkv, 1536, 12);  // QKV
  k_attn   <<<2048 * 4, 256, 0, stream>>>(qkv, btbl, xbf);                  // attn -> xbf region
  k_gemm<0><<<784 * 4,  256, 0, stream>>>(xbf, wpT, b_proj, out, 512, 4);   // proj -> d_out
}

// Round 7
// 907.237 us; speedup vs baseline: 1.0554x; 1.0213x over previous
//
#include <hip/hip_runtime.h>

// PAWSA (Swin window attention): x @ Wqkv -> per-window biased softmax attn -> @ Wproj
// Round 6 resubmit (broker timeout x2 on this kernel; identical to round 4):
// GEMM = double-buffered LDS + global_load_lds w16 (m99/m100 structure,
// 839-890 TF evidence). Issue next K-slice DMA into buf^1 BEFORE compute of buf,
// one barrier per K-step (its vmcnt(0) drain lands after compute has hidden the
// load latency). Attn unchanged from round 3 (stride-68, 3 blocks/CU).

typedef unsigned short u16;
typedef __attribute__((ext_vector_type(8))) short bf16x8;
typedef __attribute__((ext_vector_type(4))) float f32x4;

#define M_TOT 100352   // 2048 windows * 49 tokens
#define KDIM  512

// async global->LDS, 16B per lane; LDS dest is wave-uniform base + lane*16 (m104)
#define GLD16(gp, lp) __builtin_amdgcn_global_load_lds( \
    (const __attribute__((address_space(1))) void*)(gp), \
    (__attribute__((address_space(3))) void*)(lp), 16, 0, 0)

__device__ __forceinline__ u16 f2bf(float x) {
  union { float f; unsigned u; } v; v.f = x;
  unsigned r = v.u + 0x7fffu + ((v.u >> 16) & 1u);   // RNE
  return (u16)(r >> 16);
}

// ---------------- prep kernels ----------------
__global__ void k_cvt(const float* __restrict__ in, u16* __restrict__ out, int n4) {
  int i = blockIdx.x * 256 + threadIdx.x;
  if (i >= n4) return;
  float4 v = ((const float4*)in)[i];
  ushort4 o; o.x = f2bf(v.x); o.y = f2bf(v.y); o.z = f2bf(v.z); o.w = f2bf(v.w);
  ((ushort4*)out)[i] = o;
}

// out[n*512 + k] = bf16(in[k*Ncols + n])   (W^T, K fixed = 512)
__global__ void k_cvtT(const float* __restrict__ in, u16* __restrict__ out,
                       int Ncols, int total) {
  int i = blockIdx.x * 256 + threadIdx.x;
  if (i >= total) return;
  int n = i >> 9, k = i & 511;
  out[i] = f2bf(in[(size_t)k * Ncols + n]);
}

// bias_tbl[h*2401 + n*49 + m] = rpb[rel_index[n*49+m]*16 + h]
__global__ void k_bias(const float* __restrict__ rpb, const int* __restrict__ ridx,
                       float* __restrict__ tbl) {
  int i = blockIdx.x * 256 + threadIdx.x;
  if (i >= 16 * 2401) return;
  int h = i / 2401, nm = i - h * 2401;
  tbl[i] = rpb[ridx[nm] * 16 + h];
}

// ---------------- GEMM: C[M x N] = A[M x 512] * BT[N x 512]^T + bias ----------------
// 128x128xBK64, 4 waves x (64x64), gload_lds w16 staging, LDS double-buffer,
// 1 barrier per K-step; loads for step k+1 in flight during compute of step k.
template<int OUTBF>
__global__ __launch_bounds__(256)
void k_gemm(const u16* __restrict__ A, const u16* __restrict__ BT,
            const float* __restrict__ bias, void* __restrict__ outp,
            int N, int ntiles) {
  __shared__ u16 smem[2][2][128 * 64];          // [buf][A/B][row][k]  64 KB
  const int tid  = threadIdx.x;
  const int total = (int)gridDim.x;             // multiple of 8 by construction
  const int logical = ((int)blockIdx.x & 7) * (total >> 3) + ((int)blockIdx.x >> 3);
  const int mtb = logical / ntiles, ntb = logical % ntiles;
  const int lane = tid & 63, wave = tid >> 6;
  const int l15 = lane & 15, g4 = lane >> 4;
  const int wm = (wave >> 1) * 64, wn = (wave & 1) * 64;

  const char* gA = (const char*)(A  + (size_t)mtb * (128 * KDIM));
  const char* gB = (const char*)(BT + (size_t)ntb * (128 * KDIM));
  // one GLD16 covers 8 rows (8 x 128 B = 1 KB): lane l -> row l>>3, byte (l&7)*16
  const int lrow = lane >> 3;
  const int lcol = (lane & 7) * 16;

  f32x4 zero4 = {0.f, 0.f, 0.f, 0.f};
  f32x4 acc[4][4];
#pragma unroll
  for (int a = 0; a < 4; ++a)
#pragma unroll
    for (int b = 0; b < 4; ++b) acc[a][b] = zero4;

  // ---- stage K-step 0 into buf 0 ----
#pragma unroll
  for (int i = 0; i < 4; ++i) {
    const int r0 = wave * 32 + i * 8;
    GLD16(gA + (size_t)(r0 + lrow) * 1024 + lcol, &smem[0][0][r0 * 64]);
    GLD16(gB + (size_t)(r0 + lrow) * 1024 + lcol, &smem[0][1][r0 * 64]);
  }
  __syncthreads();                              // vmcnt(0) drain + barrier

  for (int ks = 0; ks < 8; ++ks) {
    const int buf = ks & 1;
    if (ks < 7) {                               // DMA next slice into buf^1 (no wait)
      const int koff = (ks + 1) * 128;
#pragma unroll
      for (int i = 0; i < 4; ++i) {
        const int r0 = wave * 32 + i * 8;
        GLD16(gA + (size_t)(r0 + lrow) * 1024 + koff + lcol, &smem[buf ^ 1][0][r0 * 64]);
        GLD16(gB + (size_t)(r0 + lrow) * 1024 + koff + lcol, &smem[buf ^ 1][1][r0 * 64]);
      }
    }
    const u16* As = &smem[buf][0][0];
    const u16* Bs = &smem[buf][1][0];
#pragma unroll
    for (int kk = 0; kk < 2; ++kk) {
      bf16x8 af[4], bg[4];
#pragma unroll
      for (int mt = 0; mt < 4; ++mt)
        af[mt] = *(const bf16x8*)(As + (wm + mt * 16 + l15) * 64 + kk * 32 + g4 * 8);
#pragma unroll
      for (int nt = 0; nt < 4; ++nt)
        bg[nt] = *(const bf16x8*)(Bs + (wn + nt * 16 + l15) * 64 + kk * 32 + g4 * 8);
#pragma unroll
      for (int mt = 0; mt < 4; ++mt)
#pragma unroll
        for (int nt = 0; nt < 4; ++nt)
          acc[mt][nt] = __builtin_amdgcn_mfma_f32_16x16x32_bf16(af[mt], bg[nt], acc[mt][nt], 0, 0, 0);
    }
    __syncthreads();                            // reads done + vmcnt(0) drained
  }

  u16*  outb = (u16*)outp;
  float* outf = (float*)outp;
#pragma unroll
  for (int nt = 0; nt < 4; ++nt) {
    const int cg = ntb * 128 + wn + nt * 16 + l15;
    const float bv = bias[cg];
#pragma unroll
    for (int mt = 0; mt < 4; ++mt) {
      const size_t rg = (size_t)mtb * 128 + wm + mt * 16 + g4 * 4;
#pragma unroll
      for (int i2 = 0; i2 < 4; ++i2) {
        float v = acc[mt][nt][i2] + bv;
        size_t off = (rg + i2) * (size_t)N + cg;
        if (OUTBF) outb[off] = f2bf(v); else outf[off] = v;
      }
    }
  }
}

// ---------------- attention: 1 block = (window, 4 heads), 1 wave per head ----------------
__global__ __launch_bounds__(256)
void k_attn(const u16* __restrict__ qkv, const float* __restrict__ btbl,
            u16* __restrict__ aout) {
  __shared__ u16 sm[4][6528];                   // per wave: P[64][68] + V^T[32][68] = 52224 B total
  const int tid = threadIdx.x;
  const int wave = tid >> 6, lane = tid & 63;
  const int l15 = lane & 15, g4 = lane >> 4;
  const int win  = (int)blockIdx.x >> 2;
  const int head = ((int)blockIdx.x & 3) * 4 + wave;
  const u16* base = qkv + (size_t)win * (49 * 1536);
  const int hoff = head * 32;
  u16* plds = sm[wave];
  u16* vt   = sm[wave] + 4352;

  // stage V^T[d][m] = V[m][d]; 256 tasks cover r in [0,64) x 4 col-groups.
  // rows r>=49 are explicit ZEROS (PV reads m up to 63; junk*0 could be NaN).
  {
    bf16x8 zz = {0, 0, 0, 0, 0, 0, 0, 0};
#pragma unroll
    for (int it = 0; it < 4; ++it) {
      int task = it * 64 + lane;
      int r = task >> 2, cg2 = task & 3;
      bf16x8 vv = zz;
      if (r < 49)
        vv = *(const bf16x8*)(base + (size_t)r * 1536 + 1024 + hoff + cg2 * 8);
#pragma unroll
      for (int j = 0; j < 8; ++j) vt[(cg2 * 8 + j) * 68 + r] = (u16)vv[j];
    }
  }

  // Q/K fragments straight from global (A: row=l15,k=8*g4+j ; B: col=l15,k=8*g4+j)
  bf16x8 aq[4], bk[4];
#pragma unroll
  for (int t = 0; t < 4; ++t) {
    aq[t] = *(const bf16x8*)(base + (size_t)(t * 16 + l15) * 1536 + hoff + g4 * 8);
    bk[t] = *(const bf16x8*)(base + (size_t)(t * 16 + l15) * 1536 + 512 + hoff + g4 * 8);
  }
  f32x4 zero4 = {0.f, 0.f, 0.f, 0.f};
  f32x4 s[4][4];
#pragma unroll
  for (int mt = 0; mt < 4; ++mt)
#pragma unroll
    for (int nt = 0; nt < 4; ++nt)
      s[mt][nt] = __builtin_amdgcn_mfma_f32_16x16x32_bf16(aq[mt], bk[nt], zero4, 0, 0, 0);

  // softmax over cols (keys); C layout: row = 16*mt + 4*g4 + i, col = 16*nt + l15
  const float* bt = btbl + head * 2401;
  const float scale = 0.17677669529663687f;     // 1/sqrt(32)
  float recip[4][4];
#pragma unroll
  for (int mt = 0; mt < 4; ++mt) {
#pragma unroll
    for (int i = 0; i < 4; ++i) {
      const int row = mt * 16 + g4 * 4 + i;
      const int rowc = row < 49 ? row : 48;
      float lv[4];
      float mx = -3.0e38f;
#pragma unroll
      for (int nt = 0; nt < 4; ++nt) {
        const int col = nt * 16 + l15;
        float v = (col < 49) ? (s[mt][nt][i] * scale + bt[rowc * 49 + col]) : -3.0e38f;
        lv[nt] = v;
        mx = fmaxf(mx, v);
      }
      mx = fmaxf(mx, __shfl_xor(mx, 1));
      mx = fmaxf(mx, __shfl_xor(mx, 2));
      mx = fmaxf(mx, __shfl_xor(mx, 4));
      mx = fmaxf(mx, __shfl_xor(mx, 8));
      float sum = 0.f;
#pragma unroll
      for (int nt = 0; nt < 4; ++nt) {
        float p = __expf(lv[nt] - mx);
        lv[nt] = p;
        sum += p;
      }
      sum += __shfl_xor(sum, 1);
      sum += __shfl_xor(sum, 2);
      sum += __shfl_xor(sum, 4);
      sum += __shfl_xor(sum, 8);
      recip[mt][i] = 1.0f / sum;
#pragma unroll
      for (int nt = 0; nt < 4; ++nt)
        plds[row * 68 + nt * 16 + l15] = f2bf(lv[nt]);   // unnormalized P
    }
  }

  // O = P @ V  (A from plds, B from vt); normalize by recip at store
  f32x4 o[4][2];
#pragma unroll
  for (int mt = 0; mt < 4; ++mt)
#pragma unroll
    for (int dt = 0; dt < 2; ++dt) o[mt][dt] = zero4;
#pragma unroll
  for (int kt = 0; kt < 2; ++kt) {
    bf16x8 pa[4], vb[2];
#pragma unroll
    for (int mt = 0; mt < 4; ++mt)
      pa[mt] = *(const bf16x8*)(plds + (mt * 16 + l15) * 68 + kt * 32 + g4 * 8);
#pragma unroll
    for (int dt = 0; dt < 2; ++dt)
      vb[dt] = *(const bf16x8*)(vt + (dt * 16 + l15) * 68 + kt * 32 + g4 * 8);
#pragma unroll
    for (int mt = 0; mt < 4; ++mt)
#pragma unroll
      for (int dt = 0; dt < 2; ++dt)
        o[mt][dt] = __builtin_amdgcn_mfma_f32_16x16x32_bf16(pa[mt], vb[dt], o[mt][dt], 0, 0, 0);
  }

#pragma unroll
  for (int mt = 0; mt < 4; ++mt) {
#pragma unroll
    for (int i = 0; i < 4; ++i) {
      const int row = mt * 16 + g4 * 4 + i;
      if (row < 49) {
        u16* orow = aout + (size_t)(win * 49 + row) * 512 + hoff;
#pragma unroll
        for (int dt = 0; dt < 2; ++dt)
          orow[dt * 16 + l15] = f2bf(o[mt][dt][i] * recip[mt][i]);
      }
    }
  }
}

// ---------------- launcher ----------------
extern "C" void kernel_launch(void* const* d_in, const int* in_sizes, int n_in,
                              void* d_out, int out_size, void* d_ws, size_t ws_size,
                              hipStream_t stream) {
  const float* x      = (const float*)d_in[0];
  const float* w_qkv  = (const float*)d_in[1];
  const float* b_qkv  = (const float*)d_in[2];
  const float* rpb    = (const float*)d_in[3];
  const float* w_proj = (const float*)d_in[4];
  const float* b_proj = (const float*)d_in[5];
  const int*   ridx   = (const int*)d_in[6];
  float* out = (float*)d_out;

  // ws layout (bytes). x_bf16 region is reused for attnout after GEMM1.
  const size_t o_x   = 0;                          // 100352*512*2     = 102,760,448
  const size_t o_qkv = 102760448;                  // 100416*1536*2    = 308,477,952 (64 slack rows)
  const size_t o_wq  = o_qkv + 308477952;          // 1536*512*2       =   1,572,864
  const size_t o_wp  = o_wq + 1572864;             // 512*512*2        =     524,288
  const size_t o_bt  = o_wp + 524288;              // 16*49*49*4       =     153,664
  const size_t need  = o_bt + 153664;              // ~394 MiB
  if (ws_size < need) return;                      // failure signature: absmax == 0.171875

  char* ws = (char*)d_ws;
  u16*   xbf  = (u16*)(ws + o_x);
  u16*   qkv  = (u16*)(ws + o_qkv);
  u16*   wqT  = (u16*)(ws + o_wq);
  u16*   wpT  = (u16*)(ws + o_wp);
  float* btbl = (float*)(ws + o_bt);

  k_cvt  <<<50176, 256, 0, stream>>>(x, xbf, 12845056);          // x -> bf16
  k_cvtT <<<3072,  256, 0, stream>>>(w_qkv, wqT, 1536, 786432);  // Wqkv^T -> bf16
  k_cvtT <<<1024,  256, 0, stream>>>(w_proj, wpT, 512, 262144);  // Wproj^T -> bf16
  k_bias <<<151,   256, 0, stream>>>(rpb, ridx, btbl);           // bias table

  k_gemm<1><<<784 * 12, 256, 0, stream>>>(xbf, wqT, b_qkv, qkv, 1536, 12);  // QKV
  k_attn   <<<2048 * 4, 256, 0, stream>>>(qkv, btbl, xbf);                  // attn -> xbf region
  k_gemm<0><<<784 * 4,  256, 0, stream>>>(xbf, wpT, b_proj, out, 512, 4);   // proj -> d_out
}